// Round 1
// baseline (20140.073 us; speedup 1.0000x reference)
//
#include <hip/hip_runtime.h>
#include <math.h>

// DisplacementTensors: per-edge radial-MLP + scatter-add to nodes + per-node linear map.
// N_NODES=50000, N_EDGES=1600000, DIM_A=DIM_V=32, R0=5, LEAK=0.1
//
// d_out layout: A_a [50000*32] floats, then out_v [50000*32*3] floats.
// A_v is accumulated IN PLACE in the out_v region, then transformed in place
// by the node kernel (all readers/writers of one node are in one block; loads
// precede stores; __syncthreads between accumulate and store).

#define NN 50000
#define NE 1600000
#define DA 32

__global__ __launch_bounds__(256) void dt_edge(
    const float* __restrict__ r_ij,
    const float* __restrict__ res_emb,
    const int*   __restrict__ src,
    const int*   __restrict__ dst,
    const float* __restrict__ W1, const float* __restrict__ b1,
    const float* __restrict__ W2, const float* __restrict__ b2,
    const float* __restrict__ W3,
    float* __restrict__ A_a,   // d_out, [NN][32]
    float* __restrict__ A_v)   // d_out + NN*32, [NN][32][3]
{
    __shared__ float sW1[DA*DA];
    __shared__ float sW2[DA*DA];
    __shared__ float sW3[DA*DA];
    __shared__ float sb1[DA];
    __shared__ float sb2[DA];
    for (int i = threadIdx.x; i < DA*DA; i += 256) {
        sW1[i] = W1[i];
        sW2[i] = W2[i];
        sW3[i] = W3[i];
    }
    if (threadIdx.x < DA) {
        sb1[threadIdx.x] = b1[threadIdx.x];
        sb2[threadIdx.x] = b2[threadIdx.x];
    }
    __syncthreads();

    const int e = blockIdx.x * 256 + threadIdx.x;   // grid exactly NE/256 blocks

    // --- load displacement, radial encode ---
    const float rx = r_ij[(size_t)e*3 + 0];
    const float ry = r_ij[(size_t)e*3 + 1];
    const float rz = r_ij[(size_t)e*3 + 2];
    const float dist = sqrtf(rx*rx + ry*ry + rz*rz);

    float xa[DA];   // working vector A
    float xb[DA];   // working vector B
    const float PI_R0 = 0.62831853071795864769f;  // pi / 5
    #pragma unroll
    for (int k = 0; k < 16; ++k) {
        const float c = PI_R0 * (float)(1 + (k >> 1));
        float sph, cph;
        sincosf(c * dist, &sph, &cph);
        xa[k]      = cph;
        xa[16 + k] = sph;
    }

    // --- gather res_emb[dst] and add (vectorized 128B row) ---
    const int d = dst[e];
    const float4* er = (const float4*)(res_emb + (size_t)d * DA);
    #pragma unroll
    for (int q = 0; q < 8; ++q) {
        const float4 v = er[q];
        xa[q*4 + 0] += v.x;
        xa[q*4 + 1] += v.y;
        xa[q*4 + 2] += v.z;
        xa[q*4 + 3] += v.w;
    }

    // --- MLP: h1 = leaky(W1 x + b1) ---
    #pragma unroll
    for (int i = 0; i < DA; ++i) {
        float acc = sb1[i];
        #pragma unroll
        for (int j = 0; j < DA; ++j) acc += xa[j] * sW1[i*DA + j];
        xb[i] = (acc >= 0.0f) ? acc : 0.1f * acc;
    }
    // --- h2 = leaky(W2 h1 + b2) ---
    #pragma unroll
    for (int i = 0; i < DA; ++i) {
        float acc = sb2[i];
        #pragma unroll
        for (int j = 0; j < DA; ++j) acc += xb[j] * sW2[i*DA + j];
        xa[i] = (acc >= 0.0f) ? acc : 0.1f * acc;
    }
    // --- rad_enc = W3 h2 ---
    #pragma unroll
    for (int i = 0; i < DA; ++i) {
        float acc = 0.0f;
        #pragma unroll
        for (int j = 0; j < DA; ++j) acc += xa[j] * sW3[i*DA + j];
        xb[i] = acc;
    }

    // --- equivariant vector gate: rv = q * tanh(|q|)/|q|, q = r*1.4 ---
    const float qx = rx * 1.4f, qy = ry * 1.4f, qz = rz * 1.4f;
    const float nq = sqrtf(qx*qx + qy*qy + qz*qz);
    const float sc = (nq > 0.0f) ? (tanhf(nq) / nq) : 0.0f;
    const float vx = qx * sc, vy = qy * sc, vz = qz * sc;

    // --- scatter-add to node accumulators ---
    const int s = src[e];
    float* pa = A_a + (size_t)s * DA;
    float* pv = A_v + (size_t)s * (DA*3);
    #pragma unroll
    for (int i = 0; i < DA; ++i) {
        atomicAdd(&pa[i], xb[i]);
    }
    #pragma unroll
    for (int i = 0; i < DA; ++i) {
        atomicAdd(&pv[i*3 + 0], xb[i] * vx);
        atomicAdd(&pv[i*3 + 1], xb[i] * vy);
        atomicAdd(&pv[i*3 + 2], xb[i] * vz);
    }
}

// out_v[n][v][d] = sum_a Wv[v][a] * A_v[n][a][d], in place over A_v.
// thread t -> (n = t>>5, v = t&31); all 32 threads of a node are in one block.
__global__ __launch_bounds__(256) void dt_node(
    const float* __restrict__ Wv,
    float* Av_out)   // aliased read+write, deliberately NOT restrict
{
    __shared__ float sWv[DA*DA];
    for (int i = threadIdx.x; i < DA*DA; i += 256) sWv[i] = Wv[i];
    __syncthreads();

    const int t = blockIdx.x * 256 + threadIdx.x;   // grid exactly NN*32/256
    const int n = t >> 5;
    const int v = t & 31;

    const float* av = Av_out + (size_t)n * (DA*3);
    float a0 = 0.0f, a1 = 0.0f, a2 = 0.0f;
    #pragma unroll
    for (int a = 0; a < DA; ++a) {
        const float w = sWv[v*DA + a];
        a0 += w * av[a*3 + 0];
        a1 += w * av[a*3 + 1];
        a2 += w * av[a*3 + 2];
    }
    __syncthreads();   // all loads of this block's nodes complete before any store
    float* out = Av_out + (size_t)n * (DA*3) + v*3;
    out[0] = a0;
    out[1] = a1;
    out[2] = a2;
}

extern "C" void kernel_launch(void* const* d_in, const int* in_sizes, int n_in,
                              void* d_out, int out_size, void* d_ws, size_t ws_size,
                              hipStream_t stream) {
    const float* r_ij    = (const float*)d_in[0];
    const float* res_emb = (const float*)d_in[1];
    const int*   src     = (const int*)d_in[2];
    const int*   dst     = (const int*)d_in[3];
    const float* W1      = (const float*)d_in[4];
    const float* b1      = (const float*)d_in[5];
    const float* W2      = (const float*)d_in[6];
    const float* b2      = (const float*)d_in[7];
    const float* W3      = (const float*)d_in[8];
    const float* Wv      = (const float*)d_in[9];

    float* A_a = (float*)d_out;                    // [NN][32]
    float* A_v = (float*)d_out + (size_t)NN * DA;  // [NN][32][3], becomes out_v

    // zero the accumulators (whole output; harness doesn't re-poison between replays)
    hipMemsetAsync(d_out, 0, (size_t)out_size * sizeof(float), stream);

    dt_edge<<<NE / 256, 256, 0, stream>>>(r_ij, res_emb, src, dst,
                                          W1, b1, W2, b2, W3, A_a, A_v);
    dt_node<<<(NN * DA) / 256, 256, 0, stream>>>(Wv, A_v);
}

// Round 2
// 812.070 us; speedup vs baseline: 24.8009x; 24.8009x over previous
//
#include <hip/hip_runtime.h>
#include <math.h>

// DisplacementTensors: per-edge radial-MLP + segment-sum to nodes + per-node linear map.
// N_NODES=50000, N_EDGES=1600000, DIM_A=DIM_V=32, R0=5, LEAK=0.1
//
// Round 2 strategy: round 1 was 99% global-f32-atomic stalls (204.8M atomics,
// 33 GB coherence traffic, VALUBusy=1%). Replace with CSR build (int atomics,
// 128x fewer) + one wave-per-node gather kernel that recomputes the MLP in
// lane-per-output-dim form and accumulates in registers. Zero float atomics.
//
// d_out layout: A_a [50000*32] floats, then out_v [50000*32*3] floats.
// ws layout: counts[NN] | offsets[NN+1] | rank[NE] | edge_ids[NE]  (13.2 MB)

#define NN 50000
#define NE 1600000
#define DA 32
#define PI_R0 0.62831853071795864769f  // pi / 5

__device__ __forceinline__ void wsync() {
    // intra-wave LDS handoff: wave is lockstep; just drain the DS queue.
    asm volatile("s_waitcnt lgkmcnt(0)" ::: "memory");
}

// ---------------- CSR build ----------------

__global__ __launch_bounds__(256) void k_hist(const int* __restrict__ src,
                                              int* __restrict__ counts,
                                              int* __restrict__ rank) {
    const int e = blockIdx.x * 256 + threadIdx.x;   // grid exactly NE/256
    rank[e] = atomicAdd(&counts[src[e]], 1);
}

__global__ __launch_bounds__(256) void k_scan(const int* __restrict__ counts,
                                              int* __restrict__ offsets) {
    __shared__ int part[256];
    const int CH = (NN + 255) / 256;   // 196
    const int t = threadIdx.x;
    const int base = t * CH;
    int s = 0;
    for (int k = 0; k < CH; ++k) { const int idx = base + k; if (idx < NN) s += counts[idx]; }
    part[t] = s;
    __syncthreads();
    if (t == 0) {
        int run = 0;
        for (int k = 0; k < 256; ++k) { const int v = part[k]; part[k] = run; run += v; }
    }
    __syncthreads();
    int run = part[t];
    for (int k = 0; k < CH; ++k) {
        const int idx = base + k;
        if (idx < NN) { offsets[idx] = run; run += counts[idx]; }
    }
    if (t == 255) offsets[NN] = run;   // total == NE
}

__global__ __launch_bounds__(256) void k_scatter(const int* __restrict__ src,
                                                 const int* __restrict__ offsets,
                                                 const int* __restrict__ rank,
                                                 int* __restrict__ edge_ids) {
    const int e = blockIdx.x * 256 + threadIdx.x;
    edge_ids[offsets[src[e]] + rank[e]] = e;
}

// ---------------- gather + MLP + Wv transform ----------------
// block = 256 = 4 waves; wave w handles node blockIdx.x*4 + w.
// Within a wave: lane = (p<<5)|i, p = edge-pair slot (2 edges/iter), i = feature dim.

__global__ __launch_bounds__(256) void dt_gather(
    const float* __restrict__ r_ij,
    const float* __restrict__ res_emb,
    const int*   __restrict__ dst,
    const int*   __restrict__ offsets,
    const int*   __restrict__ edge_ids,
    const float* __restrict__ W1, const float* __restrict__ b1,
    const float* __restrict__ W2, const float* __restrict__ b2,
    const float* __restrict__ W3, const float* __restrict__ Wv,
    float* __restrict__ A_a,    // [NN][32]
    float* __restrict__ out_v)  // [NN][32][3]
{
    // transposed weights: sWt[j*32+i] = W[i][j]  -> lane i reads consecutive banks
    __shared__ float sW1t[DA*DA], sW2t[DA*DA], sW3t[DA*DA], sWvt[DA*DA];
    __shared__ float sb1[DA], sb2[DA];
    __shared__ float x_lds[4][2][DA];     // [wave][pair][dim]
    __shared__ float av_lds[4][DA][3];    // [wave][a][d]

    for (int t = threadIdx.x; t < DA*DA; t += 256) {
        const int gsrc = (t & 31) * DA + (t >> 5);   // W[i][j] with i=t&31, j=t>>5
        sW1t[t] = W1[gsrc];
        sW2t[t] = W2[gsrc];
        sW3t[t] = W3[gsrc];
        sWvt[t] = Wv[gsrc];
    }
    if (threadIdx.x < DA) {
        sb1[threadIdx.x] = b1[threadIdx.x];
        sb2[threadIdx.x] = b2[threadIdx.x];
    }
    __syncthreads();

    const int lane = threadIdx.x & 63;
    const int wv   = threadIdx.x >> 6;       // wave id in block, 0..3
    const int p    = lane >> 5;              // pair slot 0/1
    const int i    = lane & 31;              // feature dim
    const int n    = blockIdx.x * 4 + wv;    // node (grid exactly NN/4)

    const int beg = offsets[n];
    const int end = offsets[n + 1];

    float accA = 0.0f, aV0 = 0.0f, aV1 = 0.0f, aV2 = 0.0f;

    const int k16 = i & 15;
    const float coef = PI_R0 * (float)(1 + (k16 >> 1));

    for (int eo = beg; eo < end; eo += 2) {
        const int slot  = eo + p;
        const bool valid = (slot < end);
        const int eid = edge_ids[valid ? slot : beg];

        // displacement + radial encode (lane computes its own dim)
        const float rx = r_ij[eid*3 + 0];
        const float ry = r_ij[eid*3 + 1];
        const float rz = r_ij[eid*3 + 2];
        const float dist = sqrtf(rx*rx + ry*ry + rz*rz);
        float sph, cph;
        sincosf(coef * dist, &sph, &cph);
        float x = (i < 16) ? cph : sph;

        // + res_emb[dst] (coalesced 128B row per edge)
        x += res_emb[dst[eid] * DA + i];

        wsync();
        x_lds[wv][p][i] = x;
        wsync();

        // layer 1: h = leaky(W1 x + b1)
        float h = sb1[i];
        #pragma unroll
        for (int j4 = 0; j4 < 8; ++j4) {
            const float4 xv = *(const float4*)&x_lds[wv][p][j4*4];   // uniform-addr broadcast
            h += sW1t[(j4*4+0)*DA + i] * xv.x;
            h += sW1t[(j4*4+1)*DA + i] * xv.y;
            h += sW1t[(j4*4+2)*DA + i] * xv.z;
            h += sW1t[(j4*4+3)*DA + i] * xv.w;
        }
        h = (h >= 0.0f) ? h : 0.1f * h;

        wsync();
        x_lds[wv][p][i] = h;
        wsync();

        // layer 2
        float h2 = sb2[i];
        #pragma unroll
        for (int j4 = 0; j4 < 8; ++j4) {
            const float4 xv = *(const float4*)&x_lds[wv][p][j4*4];
            h2 += sW2t[(j4*4+0)*DA + i] * xv.x;
            h2 += sW2t[(j4*4+1)*DA + i] * xv.y;
            h2 += sW2t[(j4*4+2)*DA + i] * xv.z;
            h2 += sW2t[(j4*4+3)*DA + i] * xv.w;
        }
        h2 = (h2 >= 0.0f) ? h2 : 0.1f * h2;

        wsync();
        x_lds[wv][p][i] = h2;
        wsync();

        // layer 3: rad = W3 h2
        float rad = 0.0f;
        #pragma unroll
        for (int j4 = 0; j4 < 8; ++j4) {
            const float4 xv = *(const float4*)&x_lds[wv][p][j4*4];
            rad += sW3t[(j4*4+0)*DA + i] * xv.x;
            rad += sW3t[(j4*4+1)*DA + i] * xv.y;
            rad += sW3t[(j4*4+2)*DA + i] * xv.z;
            rad += sW3t[(j4*4+3)*DA + i] * xv.w;
        }

        // equivariant gate rv = q * tanh(|q|)/|q|, q = r * (7/5)
        const float qx = rx * 1.4f, qy = ry * 1.4f, qz = rz * 1.4f;
        const float nq = sqrtf(qx*qx + qy*qy + qz*qz);
        const float sc = (nq > 0.0f) ? (tanhf(nq) / nq) : 0.0f;

        if (valid) {
            accA += rad;
            aV0  += rad * (qx * sc);
            aV1  += rad * (qy * sc);
            aV2  += rad * (qz * sc);
        }
    }

    // fold the two pair-slots together (lane i gets lane i+32's partial)
    accA += __shfl_xor(accA, 32);
    aV0  += __shfl_xor(aV0, 32);
    aV1  += __shfl_xor(aV1, 32);
    aV2  += __shfl_xor(aV2, 32);

    if (lane < 32) {
        A_a[n * DA + i] = accA;
        av_lds[wv][i][0] = aV0;
        av_lds[wv][i][1] = aV1;
        av_lds[wv][i][2] = aV2;
    }
    wsync();

    // out_v[n][v][d] = sum_a Wv[v][a] * A_v[a][d]   (lane v = i)
    if (lane < 32) {
        float o0 = 0.0f, o1 = 0.0f, o2 = 0.0f;
        #pragma unroll
        for (int a = 0; a < DA; ++a) {
            const float w = sWvt[a*DA + i];
            o0 += w * av_lds[wv][a][0];
            o1 += w * av_lds[wv][a][1];
            o2 += w * av_lds[wv][a][2];
        }
        float* o = out_v + ((size_t)n * DA + i) * 3;
        o[0] = o0; o[1] = o1; o[2] = o2;
    }
}

// ---------------- fallback path (round-1 atomic version) ----------------

__global__ __launch_bounds__(256) void dt_edge_atomic(
    const float* __restrict__ r_ij, const float* __restrict__ res_emb,
    const int* __restrict__ src, const int* __restrict__ dst,
    const float* __restrict__ W1, const float* __restrict__ b1,
    const float* __restrict__ W2, const float* __restrict__ b2,
    const float* __restrict__ W3,
    float* __restrict__ A_a, float* __restrict__ A_v)
{
    __shared__ float sW1[DA*DA], sW2[DA*DA], sW3[DA*DA], sb1[DA], sb2[DA];
    for (int i = threadIdx.x; i < DA*DA; i += 256) { sW1[i]=W1[i]; sW2[i]=W2[i]; sW3[i]=W3[i]; }
    if (threadIdx.x < DA) { sb1[threadIdx.x]=b1[threadIdx.x]; sb2[threadIdx.x]=b2[threadIdx.x]; }
    __syncthreads();
    const int e = blockIdx.x * 256 + threadIdx.x;
    const float rx = r_ij[(size_t)e*3+0], ry = r_ij[(size_t)e*3+1], rz = r_ij[(size_t)e*3+2];
    const float dist = sqrtf(rx*rx + ry*ry + rz*rz);
    float xa[DA], xb[DA];
    #pragma unroll
    for (int k = 0; k < 16; ++k) {
        const float c = PI_R0 * (float)(1 + (k >> 1));
        float sph, cph; sincosf(c * dist, &sph, &cph);
        xa[k] = cph; xa[16+k] = sph;
    }
    const int d = dst[e];
    const float4* er = (const float4*)(res_emb + (size_t)d * DA);
    #pragma unroll
    for (int q = 0; q < 8; ++q) {
        const float4 v = er[q];
        xa[q*4+0]+=v.x; xa[q*4+1]+=v.y; xa[q*4+2]+=v.z; xa[q*4+3]+=v.w;
    }
    #pragma unroll
    for (int i = 0; i < DA; ++i) {
        float acc = sb1[i];
        #pragma unroll
        for (int j = 0; j < DA; ++j) acc += xa[j] * sW1[i*DA+j];
        xb[i] = (acc >= 0.0f) ? acc : 0.1f*acc;
    }
    #pragma unroll
    for (int i = 0; i < DA; ++i) {
        float acc = sb2[i];
        #pragma unroll
        for (int j = 0; j < DA; ++j) acc += xb[j] * sW2[i*DA+j];
        xa[i] = (acc >= 0.0f) ? acc : 0.1f*acc;
    }
    #pragma unroll
    for (int i = 0; i < DA; ++i) {
        float acc = 0.0f;
        #pragma unroll
        for (int j = 0; j < DA; ++j) acc += xa[j] * sW3[i*DA+j];
        xb[i] = acc;
    }
    const float qx = rx*1.4f, qy = ry*1.4f, qz = rz*1.4f;
    const float nq = sqrtf(qx*qx+qy*qy+qz*qz);
    const float sc = (nq > 0.0f) ? (tanhf(nq)/nq) : 0.0f;
    const float vx = qx*sc, vy = qy*sc, vz = qz*sc;
    const int s = src[e];
    float* pa = A_a + (size_t)s * DA;
    float* pv = A_v + (size_t)s * (DA*3);
    #pragma unroll
    for (int i = 0; i < DA; ++i) atomicAdd(&pa[i], xb[i]);
    #pragma unroll
    for (int i = 0; i < DA; ++i) {
        atomicAdd(&pv[i*3+0], xb[i]*vx);
        atomicAdd(&pv[i*3+1], xb[i]*vy);
        atomicAdd(&pv[i*3+2], xb[i]*vz);
    }
}

__global__ __launch_bounds__(256) void dt_node_atomic(const float* __restrict__ Wv, float* Av_out) {
    __shared__ float sWv[DA*DA];
    for (int i = threadIdx.x; i < DA*DA; i += 256) sWv[i] = Wv[i];
    __syncthreads();
    const int t = blockIdx.x * 256 + threadIdx.x;
    const int n = t >> 5, v = t & 31;
    const float* av = Av_out + (size_t)n * (DA*3);
    float a0=0, a1=0, a2=0;
    #pragma unroll
    for (int a = 0; a < DA; ++a) {
        const float w = sWv[v*DA+a];
        a0 += w*av[a*3+0]; a1 += w*av[a*3+1]; a2 += w*av[a*3+2];
    }
    __syncthreads();
    float* o = Av_out + (size_t)n*(DA*3) + v*3;
    o[0]=a0; o[1]=a1; o[2]=a2;
}

// ---------------- launch ----------------

extern "C" void kernel_launch(void* const* d_in, const int* in_sizes, int n_in,
                              void* d_out, int out_size, void* d_ws, size_t ws_size,
                              hipStream_t stream) {
    const float* r_ij    = (const float*)d_in[0];
    const float* res_emb = (const float*)d_in[1];
    const int*   src     = (const int*)d_in[2];
    const int*   dst     = (const int*)d_in[3];
    const float* W1      = (const float*)d_in[4];
    const float* b1      = (const float*)d_in[5];
    const float* W2      = (const float*)d_in[6];
    const float* b2      = (const float*)d_in[7];
    const float* W3      = (const float*)d_in[8];
    const float* Wv      = (const float*)d_in[9];

    float* A_a   = (float*)d_out;                    // [NN][32]
    float* out_v = (float*)d_out + (size_t)NN * DA;  // [NN][32][3]

    const size_t need = ((size_t)NN + (size_t)(NN + 1) + (size_t)NE + (size_t)NE) * sizeof(int);

    if (ws_size >= need) {
        int* counts   = (int*)d_ws;
        int* offsets  = counts + NN;
        int* rank     = offsets + NN + 1;
        int* edge_ids = rank + NE;

        hipMemsetAsync(counts, 0, (size_t)NN * sizeof(int), stream);
        k_hist   <<<NE / 256, 256, 0, stream>>>(src, counts, rank);
        k_scan   <<<1, 256, 0, stream>>>(counts, offsets);
        k_scatter<<<NE / 256, 256, 0, stream>>>(src, offsets, rank, edge_ids);
        dt_gather<<<NN / 4, 256, 0, stream>>>(r_ij, res_emb, dst, offsets, edge_ids,
                                              W1, b1, W2, b2, W3, Wv, A_a, out_v);
    } else {
        // fallback: round-1 atomic path
        hipMemsetAsync(d_out, 0, (size_t)out_size * sizeof(float), stream);
        dt_edge_atomic<<<NE / 256, 256, 0, stream>>>(r_ij, res_emb, src, dst,
                                                     W1, b1, W2, b2, W3, A_a, out_v);
        dt_node_atomic<<<(NN * DA) / 256, 256, 0, stream>>>(Wv, out_v);
    }
}

// Round 3
// 737.412 us; speedup vs baseline: 27.3118x; 1.1012x over previous
//
#include <hip/hip_runtime.h>
#include <math.h>

// DisplacementTensors: per-edge radial-MLP + segment-sum to nodes + per-node linear map.
// N_NODES=50000, N_EDGES=1600000, DIM_A=DIM_V=32, R0=5, LEAK=0.1
//
// Round 3: round 2's dt_gather (680us, 84% of total) was DS-pipe bound:
// 96 ds_read_b32 weight re-reads per 2-edge iteration + serialized LDS
// round-trips vs only 96 FMAs. Fix: W1/W2/W3 rows hoisted to 96 VGPRs/lane
// (read once), global loads software-pipelined one iteration ahead, native
// sincos/exp transcendentals. CSR build unchanged (~130us, second-order).
//
// d_out layout: A_a [50000*32] floats, then out_v [50000*32*3] floats.
// ws layout: counts[NN] | offsets[NN+1] | rank[NE] | edge_ids[NE]  (13.2 MB)

#define NN 50000
#define NE 1600000
#define DA 32
#define PI_R0 0.62831853071795864769f  // pi / 5

__device__ __forceinline__ void wsync() {
    // intra-wave LDS handoff: wave is lockstep; drain the DS queue so
    // cross-lane reads see this wave's writes.
    asm volatile("s_waitcnt lgkmcnt(0)" ::: "memory");
}

// ---------------- CSR build ----------------

__global__ __launch_bounds__(256) void k_hist(const int* __restrict__ src,
                                              int* __restrict__ counts,
                                              int* __restrict__ rank) {
    const int e = blockIdx.x * 256 + threadIdx.x;   // grid exactly NE/256
    rank[e] = atomicAdd(&counts[src[e]], 1);
}

__global__ __launch_bounds__(256) void k_scan(const int* __restrict__ counts,
                                              int* __restrict__ offsets) {
    __shared__ int part[256];
    const int CH = (NN + 255) / 256;   // 196
    const int t = threadIdx.x;
    const int base = t * CH;
    int s = 0;
    for (int k = 0; k < CH; ++k) { const int idx = base + k; if (idx < NN) s += counts[idx]; }
    part[t] = s;
    __syncthreads();
    if (t == 0) {
        int run = 0;
        for (int k = 0; k < 256; ++k) { const int v = part[k]; part[k] = run; run += v; }
    }
    __syncthreads();
    int run = part[t];
    for (int k = 0; k < CH; ++k) {
        const int idx = base + k;
        if (idx < NN) { offsets[idx] = run; run += counts[idx]; }
    }
    if (t == 255) offsets[NN] = run;   // total == NE
}

__global__ __launch_bounds__(256) void k_scatter(const int* __restrict__ src,
                                                 const int* __restrict__ offsets,
                                                 const int* __restrict__ rank,
                                                 int* __restrict__ edge_ids) {
    const int e = blockIdx.x * 256 + threadIdx.x;
    edge_ids[offsets[src[e]] + rank[e]] = e;
}

// ---------------- gather + MLP + Wv transform ----------------
// block = 256 = 4 waves; wave w handles node blockIdx.x*4 + w.
// Within a wave: lane = (p<<5)|i, p = edge-pair slot (2 edges/iter), i = feature dim.
// Weights live in VGPRs (lane i holds row i of W1/W2/W3); only the activation
// broadcast goes through LDS (8 uniform float4 reads per layer).

__global__ __launch_bounds__(256) void dt_gather(
    const float* __restrict__ r_ij,
    const float* __restrict__ res_emb,
    const int*   __restrict__ dst,
    const int*   __restrict__ offsets,
    const int*   __restrict__ edge_ids,
    const float* __restrict__ W1, const float* __restrict__ b1,
    const float* __restrict__ W2, const float* __restrict__ b2,
    const float* __restrict__ W3, const float* __restrict__ Wv,
    float* __restrict__ A_a,    // [NN][32]
    float* __restrict__ out_v)  // [NN][32][3]
{
    // transposed staging: sWt[j*32+i] = W[i][j] -> lane i reads bank i (conflict-free)
    __shared__ float sW1t[DA*DA], sW2t[DA*DA], sW3t[DA*DA], sWvt[DA*DA];
    __shared__ float sb1[DA], sb2[DA];
    __shared__ float x_lds[4][2][DA];     // [wave][pair][dim]
    __shared__ float av_lds[4][DA][3];    // [wave][a][d]

    for (int t = threadIdx.x; t < DA*DA; t += 256) {
        const int gsrc = (t & 31) * DA + (t >> 5);   // W[i][j], i=t&31, j=t>>5
        sW1t[t] = W1[gsrc];
        sW2t[t] = W2[gsrc];
        sW3t[t] = W3[gsrc];
        sWvt[t] = Wv[gsrc];
    }
    if (threadIdx.x < DA) {
        sb1[threadIdx.x] = b1[threadIdx.x];
        sb2[threadIdx.x] = b2[threadIdx.x];
    }
    __syncthreads();

    const int lane = threadIdx.x & 63;
    const int wv   = threadIdx.x >> 6;       // wave id in block, 0..3
    const int p    = lane >> 5;              // pair slot 0/1
    const int i    = lane & 31;              // feature dim
    const int n    = blockIdx.x * 4 + wv;    // node (grid exactly NN/4)

    // hoist weight rows into registers: w1r[j] = W1[i][j]
    float w1r[DA], w2r[DA], w3r[DA];
    #pragma unroll
    for (int j = 0; j < DA; ++j) {
        w1r[j] = sW1t[j*DA + i];
        w2r[j] = sW2t[j*DA + i];
        w3r[j] = sW3t[j*DA + i];
    }
    const float b1r = sb1[i];
    const float b2r = sb2[i];

    const int beg = offsets[n];
    const int end = offsets[n + 1];

    float accA = 0.0f, aV0 = 0.0f, aV1 = 0.0f, aV2 = 0.0f;

    const float coef = PI_R0 * (float)(1 + ((i & 15) >> 1));   // radians per unit dist

    if (beg < end) {
        // prefetch iteration 0
        int slot = beg + p;
        bool val = (slot < end);
        int eid  = edge_ids[val ? slot : beg];
        float rx = r_ij[eid*3 + 0];
        float ry = r_ij[eid*3 + 1];
        float rz = r_ij[eid*3 + 2];
        float emb = res_emb[dst[eid]*DA + i];

        for (int eo = beg; eo < end; eo += 2) {
            // consume current, then immediately issue next iteration's loads
            const float crx = rx, cry = ry, crz = rz, cemb = emb;
            const bool  cval = val;

            slot = eo + 2 + p;
            val = (slot < end);
            const int neid = edge_ids[val ? slot : beg];
            rx = r_ij[neid*3 + 0];
            ry = r_ij[neid*3 + 1];
            rz = r_ij[neid*3 + 2];
            emb = res_emb[dst[neid]*DA + i];

            // radial encode (native sincos; phase <= ~9 revolutions, in HW range)
            const float dist = sqrtf(crx*crx + cry*cry + crz*crz);
            float sph, cph;
            __sincosf(coef * dist, &sph, &cph);
            const float x = ((i < 16) ? cph : sph) + cemb;

            x_lds[wv][p][i] = x;
            wsync();

            // layer 1: h = leaky(W1 x + b1)   (weights in VGPR, x broadcast from LDS)
            float h = b1r;
            #pragma unroll
            for (int j4 = 0; j4 < 8; ++j4) {
                const float4 xv = *(const float4*)&x_lds[wv][p][j4*4];
                h += w1r[j4*4+0]*xv.x + w1r[j4*4+1]*xv.y
                   + w1r[j4*4+2]*xv.z + w1r[j4*4+3]*xv.w;
            }
            h = (h >= 0.0f) ? h : 0.1f * h;

            x_lds[wv][p][i] = h;   // per-wave DS ordering: prior reads retire first
            wsync();

            // layer 2
            float h2 = b2r;
            #pragma unroll
            for (int j4 = 0; j4 < 8; ++j4) {
                const float4 xv = *(const float4*)&x_lds[wv][p][j4*4];
                h2 += w2r[j4*4+0]*xv.x + w2r[j4*4+1]*xv.y
                    + w2r[j4*4+2]*xv.z + w2r[j4*4+3]*xv.w;
            }
            h2 = (h2 >= 0.0f) ? h2 : 0.1f * h2;

            x_lds[wv][p][i] = h2;
            wsync();

            // layer 3: rad = W3 h2
            float rad = 0.0f;
            #pragma unroll
            for (int j4 = 0; j4 < 8; ++j4) {
                const float4 xv = *(const float4*)&x_lds[wv][p][j4*4];
                rad += w3r[j4*4+0]*xv.x + w3r[j4*4+1]*xv.y
                     + w3r[j4*4+2]*xv.z + w3r[j4*4+3]*xv.w;
            }

            // equivariant gate: rv = q * tanh(|q|)/|q|, q = r * 1.4
            const float qx = crx*1.4f, qy = cry*1.4f, qz = crz*1.4f;
            const float nq = sqrtf(qx*qx + qy*qy + qz*qz);
            const float e2 = __expf(2.0f * nq);
            // tanh(n)/n = (e^{2n}-1) / ((e^{2n}+1) n)
            const float sc = (nq > 0.0f)
                ? (e2 - 1.0f) * __builtin_amdgcn_rcpf((e2 + 1.0f) * nq)
                : 0.0f;

            if (cval) {
                accA += rad;
                aV0  += rad * (qx * sc);
                aV1  += rad * (qy * sc);
                aV2  += rad * (qz * sc);
            }
        }
    }

    // fold the two pair-slots (lane i += lane i+32)
    accA += __shfl_xor(accA, 32);
    aV0  += __shfl_xor(aV0, 32);
    aV1  += __shfl_xor(aV1, 32);
    aV2  += __shfl_xor(aV2, 32);

    if (lane < 32) {
        A_a[n * DA + i] = accA;
        av_lds[wv][i][0] = aV0;
        av_lds[wv][i][1] = aV1;
        av_lds[wv][i][2] = aV2;
    }
    wsync();

    // out_v[n][v][d] = sum_a Wv[v][a] * A_v[a][d]   (lane v = i; Wv from LDS)
    if (lane < 32) {
        float o0 = 0.0f, o1 = 0.0f, o2 = 0.0f;
        #pragma unroll
        for (int a = 0; a < DA; ++a) {
            const float w = sWvt[a*DA + i];
            o0 += w * av_lds[wv][a][0];
            o1 += w * av_lds[wv][a][1];
            o2 += w * av_lds[wv][a][2];
        }
        float* o = out_v + ((size_t)n * DA + i) * 3;
        o[0] = o0; o[1] = o1; o[2] = o2;
    }
}

// ---------------- fallback path (atomic version, used only if ws too small) ----------------

__global__ __launch_bounds__(256) void dt_edge_atomic(
    const float* __restrict__ r_ij, const float* __restrict__ res_emb,
    const int* __restrict__ src, const int* __restrict__ dst,
    const float* __restrict__ W1, const float* __restrict__ b1,
    const float* __restrict__ W2, const float* __restrict__ b2,
    const float* __restrict__ W3,
    float* __restrict__ A_a, float* __restrict__ A_v)
{
    __shared__ float sW1[DA*DA], sW2[DA*DA], sW3[DA*DA], sb1[DA], sb2[DA];
    for (int i = threadIdx.x; i < DA*DA; i += 256) { sW1[i]=W1[i]; sW2[i]=W2[i]; sW3[i]=W3[i]; }
    if (threadIdx.x < DA) { sb1[threadIdx.x]=b1[threadIdx.x]; sb2[threadIdx.x]=b2[threadIdx.x]; }
    __syncthreads();
    const int e = blockIdx.x * 256 + threadIdx.x;
    const float rx = r_ij[(size_t)e*3+0], ry = r_ij[(size_t)e*3+1], rz = r_ij[(size_t)e*3+2];
    const float dist = sqrtf(rx*rx + ry*ry + rz*rz);
    float xa[DA], xb[DA];
    #pragma unroll
    for (int k = 0; k < 16; ++k) {
        const float c = PI_R0 * (float)(1 + (k >> 1));
        float sph, cph; __sincosf(c * dist, &sph, &cph);
        xa[k] = cph; xa[16+k] = sph;
    }
    const int d = dst[e];
    const float4* er = (const float4*)(res_emb + (size_t)d * DA);
    #pragma unroll
    for (int q = 0; q < 8; ++q) {
        const float4 v = er[q];
        xa[q*4+0]+=v.x; xa[q*4+1]+=v.y; xa[q*4+2]+=v.z; xa[q*4+3]+=v.w;
    }
    #pragma unroll
    for (int i = 0; i < DA; ++i) {
        float acc = sb1[i];
        #pragma unroll
        for (int j = 0; j < DA; ++j) acc += xa[j] * sW1[i*DA+j];
        xb[i] = (acc >= 0.0f) ? acc : 0.1f*acc;
    }
    #pragma unroll
    for (int i = 0; i < DA; ++i) {
        float acc = sb2[i];
        #pragma unroll
        for (int j = 0; j < DA; ++j) acc += xb[j] * sW2[i*DA+j];
        xa[i] = (acc >= 0.0f) ? acc : 0.1f*acc;
    }
    #pragma unroll
    for (int i = 0; i < DA; ++i) {
        float acc = 0.0f;
        #pragma unroll
        for (int j = 0; j < DA; ++j) acc += xa[j] * sW3[i*DA+j];
        xb[i] = acc;
    }
    const float qx = rx*1.4f, qy = ry*1.4f, qz = rz*1.4f;
    const float nq = sqrtf(qx*qx+qy*qy+qz*qz);
    const float sc = (nq > 0.0f) ? (tanhf(nq)/nq) : 0.0f;
    const float vx = qx*sc, vy = qy*sc, vz = qz*sc;
    const int s = src[e];
    float* pa = A_a + (size_t)s * DA;
    float* pv = A_v + (size_t)s * (DA*3);
    #pragma unroll
    for (int i = 0; i < DA; ++i) atomicAdd(&pa[i], xb[i]);
    #pragma unroll
    for (int i = 0; i < DA; ++i) {
        atomicAdd(&pv[i*3+0], xb[i]*vx);
        atomicAdd(&pv[i*3+1], xb[i]*vy);
        atomicAdd(&pv[i*3+2], xb[i]*vz);
    }
}

__global__ __launch_bounds__(256) void dt_node_atomic(const float* __restrict__ Wv, float* Av_out) {
    __shared__ float sWv[DA*DA];
    for (int i = threadIdx.x; i < DA*DA; i += 256) sWv[i] = Wv[i];
    __syncthreads();
    const int t = blockIdx.x * 256 + threadIdx.x;
    const int n = t >> 5, v = t & 31;
    const float* av = Av_out + (size_t)n * (DA*3);
    float a0=0, a1=0, a2=0;
    #pragma unroll
    for (int a = 0; a < DA; ++a) {
        const float w = sWv[v*DA+a];
        a0 += w*av[a*3+0]; a1 += w*av[a*3+1]; a2 += w*av[a*3+2];
    }
    __syncthreads();
    float* o = Av_out + (size_t)n*(DA*3) + v*3;
    o[0]=a0; o[1]=a1; o[2]=a2;
}

// ---------------- launch ----------------

extern "C" void kernel_launch(void* const* d_in, const int* in_sizes, int n_in,
                              void* d_out, int out_size, void* d_ws, size_t ws_size,
                              hipStream_t stream) {
    const float* r_ij    = (const float*)d_in[0];
    const float* res_emb = (const float*)d_in[1];
    const int*   src     = (const int*)d_in[2];
    const int*   dst     = (const int*)d_in[3];
    const float* W1      = (const float*)d_in[4];
    const float* b1      = (const float*)d_in[5];
    const float* W2      = (const float*)d_in[6];
    const float* b2      = (const float*)d_in[7];
    const float* W3      = (const float*)d_in[8];
    const float* Wv      = (const float*)d_in[9];

    float* A_a   = (float*)d_out;                    // [NN][32]
    float* out_v = (float*)d_out + (size_t)NN * DA;  // [NN][32][3]

    const size_t need = ((size_t)NN + (size_t)(NN + 1) + (size_t)NE + (size_t)NE) * sizeof(int);

    if (ws_size >= need) {
        int* counts   = (int*)d_ws;
        int* offsets  = counts + NN;
        int* rank     = offsets + NN + 1;
        int* edge_ids = rank + NE;

        hipMemsetAsync(counts, 0, (size_t)NN * sizeof(int), stream);
        k_hist   <<<NE / 256, 256, 0, stream>>>(src, counts, rank);
        k_scan   <<<1, 256, 0, stream>>>(counts, offsets);
        k_scatter<<<NE / 256, 256, 0, stream>>>(src, offsets, rank, edge_ids);
        dt_gather<<<NN / 4, 256, 0, stream>>>(r_ij, res_emb, dst, offsets, edge_ids,
                                              W1, b1, W2, b2, W3, Wv, A_a, out_v);
    } else {
        // fallback: atomic path
        hipMemsetAsync(d_out, 0, (size_t)out_size * sizeof(float), stream);
        dt_edge_atomic<<<NE / 256, 256, 0, stream>>>(r_ij, res_emb, src, dst,
                                                     W1, b1, W2, b2, W3, A_a, out_v);
        dt_node_atomic<<<(NN * DA) / 256, 256, 0, stream>>>(Wv, out_v);
    }
}

// Round 4
// 576.103 us; speedup vs baseline: 34.9591x; 1.2800x over previous
//
#include <hip/hip_runtime.h>
#include <math.h>

// DisplacementTensors: per-edge radial-MLP + segment-sum to nodes + per-node linear map.
// N_NODES=50000, N_EDGES=1600000, DIM_A=DIM_V=32, R0=5, LEAK=0.1
//
// Round 4: round 3's dt_gather stayed DS-bound (VGPR=72 proves the weight
// hoist was rematerialized back into per-iteration LDS reads; ~63 DS ops vs
// 48 FMAs per edge, plus 3 serialized LDS round-trips). Restructure:
// one-edge-per-lane MLP (weights via UNIFORM ds_read_b128 broadcast -> 12 DS
// instr/edge, no intra-MLP round-trips, 48 FMA instr/edge = the 63us VALU
// floor), over CSR-sorted edge windows of 64 slots per wave. Wave transposes
// rad+rv through its own padded LDS region (no block barrier), segment-reduces
// its window serially (node id wave-uniform), and flushes ~3 node partials
// with fire-and-forget atomics (~10M total, vs 204.8M in round 1).
// Phase B (dt_node) applies Wv in place over the A_v accumulators.
//
// d_out layout: A_a [50000*32] floats, then out_v [50000*32*3] floats.
// ws layout: counts[NN] | offsets[NN+1] | rank[NE] | edge_ids[NE]  (13.2 MB)

#define NN 50000
#define NE 1600000
#define DA 32
#define PI_R0 0.62831853071795864769f  // pi / 5

__device__ __forceinline__ void wsync() {
    // intra-wave LDS handoff: wave is lockstep; drain the DS queue so
    // cross-lane reads see this wave's writes. ("memory" clobber orders
    // the surrounding ds ops; no register-only ops depend on this.)
    asm volatile("s_waitcnt lgkmcnt(0)" ::: "memory");
}

// ---------------- CSR build ----------------

__global__ __launch_bounds__(256) void k_hist(const int* __restrict__ src,
                                              int* __restrict__ counts,
                                              int* __restrict__ rank) {
    const int e = blockIdx.x * 256 + threadIdx.x;   // grid exactly NE/256
    rank[e] = atomicAdd(&counts[src[e]], 1);
}

__global__ __launch_bounds__(256) void k_scan(const int* __restrict__ counts,
                                              int* __restrict__ offsets) {
    __shared__ int part[256];
    const int CH = (NN + 255) / 256;   // 196
    const int t = threadIdx.x;
    const int base = t * CH;
    int s = 0;
    for (int k = 0; k < CH; ++k) { const int idx = base + k; if (idx < NN) s += counts[idx]; }
    part[t] = s;
    __syncthreads();
    if (t == 0) {
        int run = 0;
        for (int k = 0; k < 256; ++k) { const int v = part[k]; part[k] = run; run += v; }
    }
    __syncthreads();
    int run = part[t];
    for (int k = 0; k < CH; ++k) {
        const int idx = base + k;
        if (idx < NN) { offsets[idx] = run; run += counts[idx]; }
    }
    if (t == 255) offsets[NN] = run;   // total == NE
}

__global__ __launch_bounds__(256) void k_scatter(const int* __restrict__ src,
                                                 const int* __restrict__ offsets,
                                                 const int* __restrict__ rank,
                                                 int* __restrict__ edge_ids) {
    const int e = blockIdx.x * 256 + threadIdx.x;
    edge_ids[offsets[src[e]] + rank[e]] = e;
}

// ---------------- phase A: per-lane MLP over CSR windows + segmented flush ----------------
// block = 256 = 4 waves; wave handles 64 consecutive CSR slots (edges sorted
// by src). Per-lane: full MLP with uniform-broadcast LDS weight reads. Then
// wave-local transpose via padded LDS, serial segmented reduce (node id is
// wave-uniform per slot), atomic flush per node-segment.

__global__ __launch_bounds__(256, 2) void dt_window(
    const float* __restrict__ r_ij,
    const float* __restrict__ res_emb,
    const int*   __restrict__ src,
    const int*   __restrict__ dst,
    const int*   __restrict__ edge_ids,
    const float* __restrict__ W1, const float* __restrict__ b1,
    const float* __restrict__ W2, const float* __restrict__ b2,
    const float* __restrict__ W3,
    float* __restrict__ A_a,    // [NN][32]  (accumulates, pre-zeroed)
    float* __restrict__ out_v)  // [NN][32][3] (accumulates raw A_v, pre-zeroed)
{
    __shared__ float sW1[DA*DA], sW2[DA*DA], sW3[DA*DA];   // row-major
    __shared__ float sb1[DA], sb2[DA];
    __shared__ float  rad_lds[4][64][36];   // [wave][slot][dim], pad 36 for b128-aligned rows
    __shared__ float4 rvn_lds[4][64];       // [wave][slot] = (vx, vy, vz, bits(node))

    for (int t = threadIdx.x; t < DA*DA; t += 256) {
        sW1[t] = W1[t]; sW2[t] = W2[t]; sW3[t] = W3[t];
    }
    if (threadIdx.x < DA) { sb1[threadIdx.x] = b1[threadIdx.x]; sb2[threadIdx.x] = b2[threadIdx.x]; }
    __syncthreads();

    const int tid  = threadIdx.x;
    const int wv   = tid >> 6;
    const int lane = tid & 63;
    const int slot = blockIdx.x * 256 + tid;   // grid exactly NE/256

    const int eid  = edge_ids[slot];
    const int node = src[eid];

    const float rx = r_ij[eid*3 + 0];
    const float ry = r_ij[eid*3 + 1];
    const float rz = r_ij[eid*3 + 2];
    const float dist = sqrtf(rx*rx + ry*ry + rz*rz);

    // radial encode + gather res_emb[dst]
    float xa[DA], xb[DA];
    #pragma unroll
    for (int k = 0; k < 16; ++k) {
        float sph, cph;
        __sincosf(PI_R0 * (float)(1 + (k >> 1)) * dist, &sph, &cph);
        xa[k] = cph; xa[16 + k] = sph;
    }
    const float4* er = (const float4*)(res_emb + (size_t)dst[eid] * DA);
    #pragma unroll
    for (int q = 0; q < 8; ++q) {
        const float4 v = er[q];
        xa[q*4+0] += v.x; xa[q*4+1] += v.y; xa[q*4+2] += v.z; xa[q*4+3] += v.w;
    }

    // layer 1: xb = leaky(W1 xa + b1)   (uniform-address b128 weight broadcasts)
    #pragma unroll
    for (int i = 0; i < DA; ++i) {
        float acc = sb1[i];
        #pragma unroll
        for (int j4 = 0; j4 < 8; ++j4) {
            const float4 w = *(const float4*)&sW1[i*DA + j4*4];
            acc += w.x*xa[j4*4+0] + w.y*xa[j4*4+1] + w.z*xa[j4*4+2] + w.w*xa[j4*4+3];
        }
        xb[i] = (acc >= 0.0f) ? acc : 0.1f * acc;
    }
    // layer 2: xa = leaky(W2 xb + b2)
    #pragma unroll
    for (int i = 0; i < DA; ++i) {
        float acc = sb2[i];
        #pragma unroll
        for (int j4 = 0; j4 < 8; ++j4) {
            const float4 w = *(const float4*)&sW2[i*DA + j4*4];
            acc += w.x*xb[j4*4+0] + w.y*xb[j4*4+1] + w.z*xb[j4*4+2] + w.w*xb[j4*4+3];
        }
        xa[i] = (acc >= 0.0f) ? acc : 0.1f * acc;
    }
    // layer 3: xb = W3 xa
    #pragma unroll
    for (int i = 0; i < DA; ++i) {
        float acc = 0.0f;
        #pragma unroll
        for (int j4 = 0; j4 < 8; ++j4) {
            const float4 w = *(const float4*)&sW3[i*DA + j4*4];
            acc += w.x*xa[j4*4+0] + w.y*xa[j4*4+1] + w.z*xa[j4*4+2] + w.w*xa[j4*4+3];
        }
        xb[i] = acc;
    }

    // equivariant gate: rv = q * tanh(|q|)/|q|, q = r * (7/5)
    const float qx = rx*1.4f, qy = ry*1.4f, qz = rz*1.4f;
    const float nq = sqrtf(qx*qx + qy*qy + qz*qz);
    const float e2 = __expf(2.0f * nq);
    const float sc = (nq > 0.0f)
        ? (e2 - 1.0f) * __builtin_amdgcn_rcpf((e2 + 1.0f) * nq)
        : 0.0f;

    // stash this lane's rad row + (rv, node) into the wave's LDS region
    float* rrow = rad_lds[wv][lane];
    #pragma unroll
    for (int q = 0; q < 8; ++q) {
        *(float4*)&rrow[q*4] = make_float4(xb[q*4+0], xb[q*4+1], xb[q*4+2], xb[q*4+3]);
    }
    rvn_lds[wv][lane] = make_float4(qx*sc, qy*sc, qz*sc, __int_as_float(node));
    wsync();   // wave-local region only; no block barrier needed

    // ---- serial segmented reduce over the wave's 64 slots ----
    // lane = (p<<5)|i; every lane accumulates all 4 sums for dim i;
    // at flush p=0 writes {A_a, v0}, p=1 writes {v1, v2}.
    const int p = lane >> 5;
    const int i = lane & 31;

    float accA = 0.0f, a0 = 0.0f, a1 = 0.0f, a2 = 0.0f;
    int cur = __float_as_int(rvn_lds[wv][0].w);

    for (int l = 0; l < 64; ++l) {
        const float4 rvn = rvn_lds[wv][l];          // uniform b128 broadcast
        const int nd = __float_as_int(rvn.w);       // wave-uniform
        const float rd = rad_lds[wv][l][i];         // rows: 32 consecutive banks, 2-way p-broadcast
        if (nd != cur) {                            // wave-uniform branch
            if (p == 0) {
                atomicAdd(&A_a[cur*DA + i], accA);
                atomicAdd(&out_v[(cur*DA + i)*3 + 0], a0);
            } else {
                atomicAdd(&out_v[(cur*DA + i)*3 + 1], a1);
                atomicAdd(&out_v[(cur*DA + i)*3 + 2], a2);
            }
            accA = a0 = a1 = a2 = 0.0f;
            cur = nd;
        }
        accA += rd;
        a0 += rd * rvn.x;
        a1 += rd * rvn.y;
        a2 += rd * rvn.z;
    }
    if (p == 0) {
        atomicAdd(&A_a[cur*DA + i], accA);
        atomicAdd(&out_v[(cur*DA + i)*3 + 0], a0);
    } else {
        atomicAdd(&out_v[(cur*DA + i)*3 + 1], a1);
        atomicAdd(&out_v[(cur*DA + i)*3 + 2], a2);
    }
}

// ---------------- phase B: out_v[n][v][d] = sum_a Wv[v][a] * A_v[n][a][d], in place ----------------
// thread t -> (n = t>>5, v = t&31); all 32 threads of a node are in one block;
// loads precede stores with a barrier between.

__global__ __launch_bounds__(256) void dt_node(
    const float* __restrict__ Wv,
    float* Av_out)   // aliased read+write, deliberately NOT restrict
{
    __shared__ float sWv[DA*DA];
    for (int i = threadIdx.x; i < DA*DA; i += 256) sWv[i] = Wv[i];
    __syncthreads();

    const int t = blockIdx.x * 256 + threadIdx.x;   // grid exactly NN*32/256
    const int n = t >> 5;
    const int v = t & 31;

    const float* av = Av_out + (size_t)n * (DA*3);
    float o0 = 0.0f, o1 = 0.0f, o2 = 0.0f;
    #pragma unroll
    for (int a = 0; a < DA; ++a) {
        const float w = sWv[v*DA + a];
        o0 += w * av[a*3 + 0];
        o1 += w * av[a*3 + 1];
        o2 += w * av[a*3 + 2];
    }
    __syncthreads();   // all loads of this block's nodes complete before any store
    float* o = Av_out + (size_t)n * (DA*3) + v*3;
    o[0] = o0; o[1] = o1; o[2] = o2;
}

// ---------------- fallback path (atomic version, used only if ws too small) ----------------

__global__ __launch_bounds__(256) void dt_edge_atomic(
    const float* __restrict__ r_ij, const float* __restrict__ res_emb,
    const int* __restrict__ src, const int* __restrict__ dst,
    const float* __restrict__ W1, const float* __restrict__ b1,
    const float* __restrict__ W2, const float* __restrict__ b2,
    const float* __restrict__ W3,
    float* __restrict__ A_a, float* __restrict__ A_v)
{
    __shared__ float sW1[DA*DA], sW2[DA*DA], sW3[DA*DA], sb1[DA], sb2[DA];
    for (int i = threadIdx.x; i < DA*DA; i += 256) { sW1[i]=W1[i]; sW2[i]=W2[i]; sW3[i]=W3[i]; }
    if (threadIdx.x < DA) { sb1[threadIdx.x]=b1[threadIdx.x]; sb2[threadIdx.x]=b2[threadIdx.x]; }
    __syncthreads();
    const int e = blockIdx.x * 256 + threadIdx.x;
    const float rx = r_ij[(size_t)e*3+0], ry = r_ij[(size_t)e*3+1], rz = r_ij[(size_t)e*3+2];
    const float dist = sqrtf(rx*rx + ry*ry + rz*rz);
    float xa[DA], xb[DA];
    #pragma unroll
    for (int k = 0; k < 16; ++k) {
        float sph, cph; __sincosf(PI_R0 * (float)(1 + (k>>1)) * dist, &sph, &cph);
        xa[k] = cph; xa[16+k] = sph;
    }
    const int d = dst[e];
    const float4* er = (const float4*)(res_emb + (size_t)d * DA);
    #pragma unroll
    for (int q = 0; q < 8; ++q) {
        const float4 v = er[q];
        xa[q*4+0]+=v.x; xa[q*4+1]+=v.y; xa[q*4+2]+=v.z; xa[q*4+3]+=v.w;
    }
    #pragma unroll
    for (int i = 0; i < DA; ++i) {
        float acc = sb1[i];
        #pragma unroll
        for (int j = 0; j < DA; ++j) acc += xa[j] * sW1[i*DA+j];
        xb[i] = (acc >= 0.0f) ? acc : 0.1f*acc;
    }
    #pragma unroll
    for (int i = 0; i < DA; ++i) {
        float acc = sb2[i];
        #pragma unroll
        for (int j = 0; j < DA; ++j) acc += xb[j] * sW2[i*DA+j];
        xa[i] = (acc >= 0.0f) ? acc : 0.1f*acc;
    }
    #pragma unroll
    for (int i = 0; i < DA; ++i) {
        float acc = 0.0f;
        #pragma unroll
        for (int j = 0; j < DA; ++j) acc += xa[j] * sW3[i*DA+j];
        xb[i] = acc;
    }
    const float qx = rx*1.4f, qy = ry*1.4f, qz = rz*1.4f;
    const float nq = sqrtf(qx*qx+qy*qy+qz*qz);
    const float sc = (nq > 0.0f) ? (tanhf(nq)/nq) : 0.0f;
    const float vx = qx*sc, vy = qy*sc, vz = qz*sc;
    const int s = src[e];
    float* pa = A_a + (size_t)s * DA;
    float* pv = A_v + (size_t)s * (DA*3);
    #pragma unroll
    for (int i = 0; i < DA; ++i) atomicAdd(&pa[i], xb[i]);
    #pragma unroll
    for (int i = 0; i < DA; ++i) {
        atomicAdd(&pv[i*3+0], xb[i]*vx);
        atomicAdd(&pv[i*3+1], xb[i]*vy);
        atomicAdd(&pv[i*3+2], xb[i]*vz);
    }
}

// ---------------- launch ----------------

extern "C" void kernel_launch(void* const* d_in, const int* in_sizes, int n_in,
                              void* d_out, int out_size, void* d_ws, size_t ws_size,
                              hipStream_t stream) {
    const float* r_ij    = (const float*)d_in[0];
    const float* res_emb = (const float*)d_in[1];
    const int*   src     = (const int*)d_in[2];
    const int*   dst     = (const int*)d_in[3];
    const float* W1      = (const float*)d_in[4];
    const float* b1      = (const float*)d_in[5];
    const float* W2      = (const float*)d_in[6];
    const float* b2      = (const float*)d_in[7];
    const float* W3      = (const float*)d_in[8];
    const float* Wv      = (const float*)d_in[9];

    float* A_a   = (float*)d_out;                    // [NN][32]
    float* out_v = (float*)d_out + (size_t)NN * DA;  // [NN][32][3]

    const size_t need = ((size_t)NN + (size_t)(NN + 1) + (size_t)NE + (size_t)NE) * sizeof(int);

    // output is accumulated into -> must be zeroed every call
    hipMemsetAsync(d_out, 0, (size_t)out_size * sizeof(float), stream);

    if (ws_size >= need) {
        int* counts   = (int*)d_ws;
        int* offsets  = counts + NN;
        int* rank     = offsets + NN + 1;
        int* edge_ids = rank + NE;

        hipMemsetAsync(counts, 0, (size_t)NN * sizeof(int), stream);
        k_hist   <<<NE / 256, 256, 0, stream>>>(src, counts, rank);
        k_scan   <<<1, 256, 0, stream>>>(counts, offsets);
        k_scatter<<<NE / 256, 256, 0, stream>>>(src, offsets, rank, edge_ids);
        dt_window<<<NE / 256, 256, 0, stream>>>(r_ij, res_emb, src, dst, edge_ids,
                                                W1, b1, W2, b2, W3, A_a, out_v);
        dt_node  <<<(NN * DA) / 256, 256, 0, stream>>>(Wv, out_v);
    } else {
        dt_edge_atomic<<<NE / 256, 256, 0, stream>>>(r_ij, res_emb, src, dst,
                                                     W1, b1, W2, b2, W3, A_a, out_v);
        dt_node<<<(NN * DA) / 256, 256, 0, stream>>>(Wv, out_v);
    }
}